// Round 11
// baseline (176.443 us; speedup 1.0000x reference)
//
#include <hip/hip_runtime.h>

#define IN_F 512
#define OUT_F 1024
#define K_ACTIVE 11  // ceil(0.01 * 1024) serial MP steps
#define K_IN 6       // ceil(0.01 * 512) kwta winners

// ---- w [1024][512] f32 -> wT [512][1024] f32 ----
// wT is 2 MB: fits per-XCD L2 (4 MiB) together with w (2 MB). R6 measured fp64
// wT (4.2 MB) thrashing L2 -> 156 MB HBM fetch, +34 us. Keep f32.
__global__ __launch_bounds__(256) void transpose_w_kernel(const float* __restrict__ w,
                                                          float* __restrict__ wT) {
    __shared__ float tile[32][33];
    const int tx = threadIdx.x & 31;
    const int ty = threadIdx.x >> 5;  // 0..7
    const int i0 = blockIdx.x * 32;
    const int j0 = blockIdx.y * 32;
#pragma unroll
    for (int k = 0; k < 4; ++k)
        tile[ty + 8 * k][tx] = w[(size_t)(j0 + ty + 8 * k) * IN_F + (i0 + tx)];
    __syncthreads();
#pragma unroll
    for (int k = 0; k < 4; ++k)
        wT[(size_t)(i0 + ty + 8 * k) * OUT_F + (j0 + tx)] = tile[tx][ty + 8 * k];
}

// ---- order-preserving fp64 -> u64 key, low bits carry reversed index ----
// max(key) == max value; ties -> lowest index (exact reference tie-break).
__device__ __forceinline__ unsigned long long pack_key(double v, unsigned rev,
                                                       unsigned long long mask) {
    unsigned long long b = (unsigned long long)__double_as_longlong(v);
    unsigned long long m =
        (unsigned long long)((long long)b >> 63) | 0x8000000000000000ull;
    unsigned long long u = b ^ m;  // monotonic total order
    return (u & ~mask) | (unsigned long long)rev;
}

// ---- monotonic u32 key from the f64 HIGH word (== high word of pack_key) ----
__device__ __forceinline__ unsigned hi_key(double v) {
    const int hi = __double2hiint(v);
    return (unsigned)hi ^ ((unsigned)(hi >> 31) | 0x80000000u);
}

// ---- wave max of u32 via DPP chain (bound_ctrl=true: invalid lanes -> 0) ----
template <int C>
__device__ __forceinline__ unsigned maxdpp(unsigned v) {
    unsigned t = (unsigned)__builtin_amdgcn_update_dpp(0, (int)v, C, 0xF, 0xF, true);
    return t > v ? t : v;
}
__device__ __forceinline__ unsigned wave_umax(unsigned v) {
    v = maxdpp<0x111>(v);  // row_shr:1
    v = maxdpp<0x112>(v);  // row_shr:2
    v = maxdpp<0x114>(v);  // row_shr:4
    v = maxdpp<0x118>(v);  // row_shr:8
    v = maxdpp<0x142>(v);  // row_bcast:15
    v = maxdpp<0x143>(v);  // row_bcast:31 -> lane 63 holds wave max
    return (unsigned)__builtin_amdgcn_readlane((int)v, 63);
}

// ---- exact wave max of u64 key (rare path): high32 chain + tie resolve ----
__device__ __forceinline__ unsigned long long wave_max_key(unsigned long long k) {
    const unsigned h = (unsigned)(k >> 32), l = (unsigned)k;
    const unsigned gh = wave_umax(h);
    const unsigned long long tied = __ballot(h == gh);
    unsigned gl;
    if (__popcll(tied) == 1) {
        gl = (unsigned)__builtin_amdgcn_readlane((int)l,
                                                 (int)__ffsll((long long)tied) - 1);
    } else {
        gl = wave_umax((h == gh) ? l : 0u);
    }
    return ((unsigned long long)gh << 32) | gl;
}

// full-row axpy: r[S] += sgn * row_i[j(S)], j = (S>>2)*256 + lane*4 + (S&3).
// MODE1: 4 float4 loads, each 64 lanes x 16B = 1KB contiguous (coalesced), base
// uniform (SGPR) since i is wave-uniform.
template <int MODE>
__device__ __forceinline__ void full_axpy(double* r, const float* __restrict__ wT,
                                          const float* __restrict__ w, int i,
                                          double sgn, int lane) {
    if constexpr (MODE == 1) {
        const float* rp = wT + ((size_t)i << 10) + (lane << 2);
#pragma unroll
        for (int c = 0; c < 4; ++c) {
            const float4 f = *(const float4*)(rp + (c << 8));
            r[4 * c + 0] += sgn * (double)f.x;
            r[4 * c + 1] += sgn * (double)f.y;
            r[4 * c + 2] += sgn * (double)f.z;
            r[4 * c + 3] += sgn * (double)f.w;
        }
    } else {
#pragma unroll
        for (int S = 0; S < 16; ++S) {
            const int j = ((S >> 2) << 8) | (lane << 2) | (S & 3);
            r[S] += sgn * (double)w[(size_t)j * IN_F + i];
        }
    }
}

// ONE WAVE PER ROW. Zero barriers, zero LDS, no partner-wave parking (R8/R10's
// wave1 idled through kwta => VALUBusy capped ~45%). Persistent fp64 state:
// r[16]=32 + vd[8]=16 = 48 VGPR; transients kept u32/two-pass so peak < 64
// (the allocator's 8-waves/EU target; R3/R4 spilled here with 64 persistent).
template <int MODE>
__global__ __launch_bounds__(128) void bmp_kernel(const float* __restrict__ x,
                                                  const float* __restrict__ w,
                                                  const float* __restrict__ wT,
                                                  float* __restrict__ out, int rows) {
    const int lane = threadIdx.x & 63;
    const int row = blockIdx.x * 2 + (threadIdx.x >> 6);
    if (row >= rows) return;

    // ---- r = 2 * x @ wT, iterating active bits as a uniform scalar loop ----
    double r[16];
#pragma unroll
    for (int S = 0; S < 16; ++S) r[S] = 0.0;
    {
        const float* xrow = x + (size_t)row * IN_F;
#pragma unroll 1
        for (int c = 0; c < IN_F / 64; ++c) {
            const float xv = xrow[c * 64 + lane];
            unsigned long long m = __ballot(xv != 0.0f);  // uniform
            while (m) {  // ~6.4 active bits per 64 (10% density)
                const int b = (int)__ffsll((long long)m) - 1;
                m &= m - 1;
                full_axpy<MODE>(r, wT, w, c * 64 + b, 1.0, lane);
            }
        }
    }
#pragma unroll
    for (int S = 0; S < 16; ++S) r[S] *= 2.0;

    double vd[8];  // v = encoded @ W: i = (p>>2)*256 + lane*4 + (p&3)
#pragma unroll
    for (int p = 0; p < 8; ++p) vd[p] = 0.0;

    unsigned enc = 0;      // per-lane 16-bit slot mask over OUT slots
    unsigned selmask = 0;  // per-lane 8-bit mask of final xr slots
    int O0 = -1, O1 = -1, O2 = -1, O3 = -1, O4 = -1, O5 = -1;  // uniform

#pragma unroll 1
    for (int t = 0; t < K_ACTIVE; ++t) {
        // ---- argmax of residual over non-encoded j (lambd => exclusion) ----
        // pass 1: masked local max of u32 keys (recomputed, not stored: -16 VGPR)
        unsigned lv = 0;
#pragma unroll
        for (int S = 0; S < 16; ++S) {
            const unsigned key = hi_key(r[S]);
            lv = ((enc >> S) & 1u) ? lv : (key > lv ? key : lv);
        }
        const unsigned g = wave_umax(lv);
        const unsigned long long tied = __ballot(lv == g);
        // pass 2: match mask
        unsigned mm = 0;
#pragma unroll
        for (int S = 0; S < 16; ++S)
            mm |= (!((enc >> S) & 1u) && hi_key(r[S]) == g) ? (1u << S) : 0u;
        const int L = (int)__ffsll((long long)tied) - 1;
        const unsigned mmL = (unsigned)__builtin_amdgcn_readlane((int)mm, L);
        int bestj;
        if (__builtin_expect((__popcll(tied) == 1) && !(mmL & (mmL - 1)), 1)) {
            const int S = __ffs(mmL) - 1;  // unique global candidate
            bestj = ((S >> 2) << 8) | (L << 2) | (S & 3);
        } else {  // exact u64 resolve among u32-tied candidates (P ~ 2^-20)
            unsigned long long kb = 0;
#pragma unroll
            for (int S = 0; S < 16; ++S) {
                const int j = ((S >> 2) << 8) | (lane << 2) | (S & 3);
                const unsigned long long fk =
                    pack_key(r[S], 1023u ^ (unsigned)j, 1023ull);
                const bool cand = !((enc >> S) & 1u) && hi_key(r[S]) == g;
                kb = (cand && fk > kb) ? fk : kb;
            }
            const unsigned long long gk = wave_max_key(kb);
            bestj = 1023 ^ (int)(gk & 1023ull);
        }
        bestj = __builtin_amdgcn_readfirstlane(bestj);
        if (((bestj >> 2) & 63) == lane)
            enc |= 1u << ((((bestj >> 8) & 3) << 2) | (bestj & 3));

        // ---- v += W[bestj][:] (two 1KB-contiguous float4 loads, SGPR base) ----
        {
            const float* wr = w + ((size_t)bestj << 9) + (lane << 2);
            const float4 f0 = *(const float4*)wr;
            const float4 f1 = *(const float4*)(wr + 256);
            vd[0] += (double)f0.x;  vd[1] += (double)f0.y;
            vd[2] += (double)f0.z;  vd[3] += (double)f0.w;
            vd[4] += (double)f1.x;  vd[5] += (double)f1.y;
            vd[6] += (double)f1.z;  vd[7] += (double)f1.w;
        }

        // ---- kwta: top-6 of v, u32 keys packed once, 6 wave-local rounds ----
        int N[6];
        {
            unsigned kk[8];  // transient u32
#pragma unroll
            for (int p = 0; p < 8; ++p) kk[p] = hi_key(vd[p]);
#pragma unroll
            for (int s2 = 0; s2 < K_IN; ++s2) {
                unsigned lm = kk[0];
#pragma unroll
                for (int p = 1; p < 8; ++p) lm = kk[p] > lm ? kk[p] : lm;
                const unsigned g2 = wave_umax(lm);
                const unsigned long long tied2 = __ballot(lm == g2);
                unsigned mm2 = 0;
#pragma unroll
                for (int p = 0; p < 8; ++p) mm2 |= (kk[p] == g2) ? (1u << p) : 0u;
                const int L2 = (int)__ffsll((long long)tied2) - 1;
                const unsigned mmL2 =
                    (unsigned)__builtin_amdgcn_readlane((int)mm2, L2);
                int n;
                if (__builtin_expect((__popcll(tied2) == 1) && !(mmL2 & (mmL2 - 1)),
                                     1)) {
                    const int bp = __ffs(mmL2) - 1;
                    n = ((bp >> 2) << 8) | (L2 << 2) | (bp & 3);
                    // unique candidate: clear by value (exactly one slot matches)
#pragma unroll
                    for (int p = 0; p < 8; ++p) kk[p] = (kk[p] == g2) ? 0u : kk[p];
                } else {  // exact resolve among u32-tied candidates
                    unsigned long long kb = 0;
#pragma unroll
                    for (int p = 0; p < 8; ++p) {
                        const int i = ((p >> 2) << 8) | (lane << 2) | (p & 3);
                        const unsigned long long fk =
                            pack_key(vd[p], 511u ^ (unsigned)i, 511ull);
                        kb = (kk[p] == g2 && fk > kb) ? fk : kb;
                    }
                    const unsigned long long gk = wave_max_key(kb);
                    n = 511 ^ (int)(gk & 511ull);
                    const int ln = (n >> 2) & 63;
                    const int bp = (((n >> 8) & 1) << 2) | (n & 3);
#pragma unroll
                    for (int p = 0; p < 8; ++p)
                        kk[p] = (lane == ln && p == bp) ? 0u : kk[p];
                }
                N[s2] = __builtin_amdgcn_readfirstlane(n);
            }
            if (t == K_ACTIVE - 1) {
                selmask = 0;  // cleared keys are 0 (0 unreachable for real values)
#pragma unroll
                for (int p = 0; p < 8; ++p) selmask |= (kk[p] == 0u) ? (1u << p) : 0u;
            }
        }

        // ---- incremental residual update: set-diff of xr (uniform logic) ----
        if (t == 0) {
#pragma unroll
            for (int b = 0; b < 6; ++b) full_axpy<MODE>(r, wT, w, N[b], -1.0, lane);
        } else if (t < K_ACTIVE - 1) {
#pragma unroll
            for (int a2 = 0; a2 < 6; ++a2) {
                const int o = (a2 == 0) ? O0 : (a2 == 1) ? O1 : (a2 == 2) ? O2
                              : (a2 == 3) ? O3 : (a2 == 4) ? O4 : O5;
                const bool stay = (o == N[0]) | (o == N[1]) | (o == N[2]) |
                                  (o == N[3]) | (o == N[4]) | (o == N[5]);
                if (!stay) full_axpy<MODE>(r, wT, w, o, 1.0, lane);
            }
#pragma unroll
            for (int b2 = 0; b2 < 6; ++b2) {
                const int n = N[b2];
                const bool was = (n == O0) | (n == O1) | (n == O2) |
                                 (n == O3) | (n == O4) | (n == O5);
                if (!was) full_axpy<MODE>(r, wT, w, n, -1.0, lane);
            }
        }
        O0 = N[0]; O1 = N[1]; O2 = N[2]; O3 = N[3]; O4 = N[4]; O5 = N[5];
    }

    // ---- outputs: encoded [rows][OUT_F] then xr [rows][IN_F], coalesced ----
    float* oe = out + (size_t)row * OUT_F + (lane << 2);
#pragma unroll
    for (int c = 0; c < 4; ++c) {
        float4 v;
        v.x = (enc & (1u << (4 * c + 0))) ? 1.0f : 0.0f;
        v.y = (enc & (1u << (4 * c + 1))) ? 1.0f : 0.0f;
        v.z = (enc & (1u << (4 * c + 2))) ? 1.0f : 0.0f;
        v.w = (enc & (1u << (4 * c + 3))) ? 1.0f : 0.0f;
        *(float4*)(oe + (c << 8)) = v;
    }
    float* ox = out + (size_t)rows * OUT_F + (size_t)row * IN_F + (lane << 2);
#pragma unroll
    for (int c = 0; c < 2; ++c) {
        float4 v;
        v.x = (selmask & (1u << (4 * c + 0))) ? 1.0f : 0.0f;
        v.y = (selmask & (1u << (4 * c + 1))) ? 1.0f : 0.0f;
        v.z = (selmask & (1u << (4 * c + 2))) ? 1.0f : 0.0f;
        v.w = (selmask & (1u << (4 * c + 3))) ? 1.0f : 0.0f;
        *(float4*)(ox + (c << 8)) = v;
    }
}

extern "C" void kernel_launch(void* const* d_in, const int* in_sizes, int n_in,
                              void* d_out, int out_size, void* d_ws, size_t ws_size,
                              hipStream_t stream) {
    const float* x = (const float*)d_in[0];
    const float* w = (const float*)d_in[1];
    float* out = (float*)d_out;
    const int rows = in_sizes[0] / IN_F;  // 4096

    const size_t need_f = (size_t)IN_F * OUT_F * sizeof(float);  // 2 MB
    const int blocks = (rows + 1) / 2;  // 2 independent rows (waves) per block

    if (d_ws != nullptr && ws_size >= need_f) {
        float* wT = (float*)d_ws;
        transpose_w_kernel<<<dim3(IN_F / 32, OUT_F / 32), 256, 0, stream>>>(w, wT);
        bmp_kernel<1><<<blocks, 128, 0, stream>>>(x, w, wT, out, rows);
    } else {
        bmp_kernel<0><<<blocks, 128, 0, stream>>>(x, w, nullptr, out, rows);
    }
}

// Round 12
// 156.195 us; speedup vs baseline: 1.1296x; 1.1296x over previous
//
#include <hip/hip_runtime.h>

#define IN_F 512
#define OUT_F 1024
#define K_ACTIVE 11  // ceil(0.01 * 1024) serial MP steps
#define K_IN 6       // ceil(0.01 * 512) kwta winners

// ---- w [1024][512] f32 -> wT [513][1024] f32 (row 512 = zeros, odd-cnt pad) ----
// wT is 2.1 MB: fits per-XCD L2 (4 MiB) together with w (2 MB). R6 measured fp64
// wT (4.2 MB) thrashing L2 -> 156 MB HBM fetch, +34 us. Keep f32.
__global__ __launch_bounds__(256) void transpose_w_kernel(const float* __restrict__ w,
                                                          float* __restrict__ wT) {
    __shared__ float tile[32][33];
    const int tx = threadIdx.x & 31;
    const int ty = threadIdx.x >> 5;  // 0..7
    const int i0 = blockIdx.x * 32;
    const int j0 = blockIdx.y * 32;
#pragma unroll
    for (int k = 0; k < 4; ++k)
        tile[ty + 8 * k][tx] = w[(size_t)(j0 + ty + 8 * k) * IN_F + (i0 + tx)];
    __syncthreads();
#pragma unroll
    for (int k = 0; k < 4; ++k)
        wT[(size_t)(i0 + ty + 8 * k) * OUT_F + (j0 + tx)] = tile[tx][ty + 8 * k];
}
__global__ void zero_row_f_kernel(float* __restrict__ wT) {
    wT[(size_t)IN_F * OUT_F + blockIdx.x * 256 + threadIdx.x] = 0.0f;
}

// ---- order-preserving fp64 -> u64 key, low bits carry reversed index ----
__device__ __forceinline__ unsigned long long pack_key(double v, unsigned rev,
                                                       unsigned long long mask) {
    unsigned long long b = (unsigned long long)__double_as_longlong(v);
    unsigned long long m =
        (unsigned long long)((long long)b >> 63) | 0x8000000000000000ull;
    unsigned long long u = b ^ m;  // monotonic total order
    return (u & ~mask) | (unsigned long long)rev;
}

// ---- monotonic u32 key from the f64 HIGH word ----
__device__ __forceinline__ unsigned hi_key(double v) {
    const int hi = __double2hiint(v);
    return (unsigned)hi ^ ((unsigned)(hi >> 31) | 0x80000000u);
}

// ---- wave max of u32 via DPP chain (bound_ctrl=true: invalid lanes -> 0) ----
template <int C>
__device__ __forceinline__ unsigned maxdpp(unsigned v) {
    unsigned t = (unsigned)__builtin_amdgcn_update_dpp(0, (int)v, C, 0xF, 0xF, true);
    return t > v ? t : v;
}
__device__ __forceinline__ unsigned wave_umax(unsigned v) {
    v = maxdpp<0x111>(v);  // row_shr:1
    v = maxdpp<0x112>(v);  // row_shr:2
    v = maxdpp<0x114>(v);  // row_shr:4
    v = maxdpp<0x118>(v);  // row_shr:8
    v = maxdpp<0x142>(v);  // row_bcast:15
    v = maxdpp<0x143>(v);  // row_bcast:31 -> lane 63 holds wave max
    return (unsigned)__builtin_amdgcn_readlane((int)v, 63);
}

// ---- exact wave max of u64 key (rare path): high32 chain + tie resolve ----
__device__ __forceinline__ unsigned long long wave_max_key(unsigned long long k) {
    const unsigned h = (unsigned)(k >> 32), l = (unsigned)k;
    const unsigned gh = wave_umax(h);
    const unsigned long long tied = __ballot(h == gh);
    unsigned gl;
    if (__popcll(tied) == 1) {
        gl = (unsigned)__builtin_amdgcn_readlane((int)l,
                                                 (int)__ffsll((long long)tied) - 1);
    } else {
        gl = wave_umax((h == gh) ? l : 0u);
    }
    return ((unsigned long long)gh << 32) | gl;
}

// half-row paired add (projection): rh[s] over j = wv*512 + (s>>2)*256 + lane*4 + (s&3)
__device__ __forceinline__ void half_add2(double* rh, const float* __restrict__ wT,
                                          int i0, int i1, int lane, int wv) {
    const float* p0 = wT + ((size_t)i0 << 10) + (wv << 9) + (lane << 2);
    const float* p1 = wT + ((size_t)i1 << 10) + (wv << 9) + (lane << 2);
    const float4 f0 = *(const float4*)(p0);
    const float4 f1 = *(const float4*)(p0 + 256);
    const float4 g0 = *(const float4*)(p1);
    const float4 g1 = *(const float4*)(p1 + 256);
    rh[0] += (double)f0.x + (double)g0.x;  rh[1] += (double)f0.y + (double)g0.y;
    rh[2] += (double)f0.z + (double)g0.z;  rh[3] += (double)f0.w + (double)g0.w;
    rh[4] += (double)f1.x + (double)g1.x;  rh[5] += (double)f1.y + (double)g1.y;
    rh[6] += (double)f1.z + (double)g1.z;  rh[7] += (double)f1.w + (double)g1.w;
}

// half-row axpy (residual update): same slot layout, 2 coalesced float4 loads
__device__ __forceinline__ void half_axpy(double* rh, const float* __restrict__ wT,
                                          int i, double sgn, int lane, int wv) {
    const float* rp = wT + ((size_t)i << 10) + (wv << 9) + (lane << 2);
    const float4 f0 = *(const float4*)(rp);
    const float4 f1 = *(const float4*)(rp + 256);
    rh[0] += sgn * (double)f0.x;  rh[1] += sgn * (double)f0.y;
    rh[2] += sgn * (double)f0.z;  rh[3] += sgn * (double)f0.w;
    rh[4] += sgn * (double)f1.x;  rh[5] += sgn * (double)f1.y;
    rh[6] += sgn * (double)f1.z;  rh[7] += sgn * (double)f1.w;
}

// MODE0 fallbacks (no workspace): strided gathers from row-major w
__device__ __forceinline__ void half_add0(double* rh, const float* __restrict__ w,
                                          int i, int lane, int wv) {
#pragma unroll
    for (int s = 0; s < 8; ++s) {
        const int j = (wv << 9) | ((s >> 2) << 8) | (lane << 2) | (s & 3);
        rh[s] += (double)w[(size_t)j * IN_F + i];
    }
}
__device__ __forceinline__ void half_axpy0(double* rh, const float* __restrict__ w,
                                           int i, double sgn, int lane, int wv) {
#pragma unroll
    for (int s = 0; s < 8; ++s) {
        const int j = (wv << 9) | ((s >> 2) << 8) | (lane << 2) | (s & 3);
        rh[s] += sgn * (double)w[(size_t)j * IN_F + i];
    }
}

// 2 SYMMETRIC waves per row. Split: residual halves r[8] (fp64), argmax local
// scan, set-diff axpy. DUPLICATED on both waves: v (vd[8]) update + u32-key
// kwta -> both compute bit-identical winners => no handoff, no B2; exactly ONE
// barrier per step. Symmetric instruction streams arrive at B1 together =>
// parking (R10: wave1 idle through kwta, VALUBusy capped 44%) is eliminated.
template <int MODE>
__global__ __launch_bounds__(128) void bmp_kernel(const float* __restrict__ x,
                                                  const float* __restrict__ w,
                                                  const float* __restrict__ wT,
                                                  float* __restrict__ out, int rows) {
    __shared__ unsigned short act[IN_F + 8];
    __shared__ unsigned gu32[2][2];       // parity: argmax merge (u32 key)
    __shared__ int gjw[2][2];             // parity: argmax merge (index)
    __shared__ unsigned long long kx[2];  // rare exact cross-wave u64 merge
    const int lane = threadIdx.x & 63;
    const int wv = threadIdx.x >> 6;
    const int row = blockIdx.x;
    if (row >= rows) return;

    // ---- compacted active list of x row (both waves same ballots; wv0 writes) ----
    const float* xrow = x + (size_t)row * IN_F;
    int cnt = 0;
#pragma unroll
    for (int c = 0; c < IN_F / 64; ++c) {
        bool pbit = xrow[c * 64 + lane] != 0.0f;
        unsigned long long m = __ballot(pbit);
        int pre = __popcll(m & ((1ull << lane) - 1ull));
        if (wv == 0 && pbit) act[cnt + pre] = (unsigned short)(c * 64 + lane);
        cnt += __popcll(m);
    }
    if (wv == 0 && lane < 2) act[cnt + lane] = (unsigned short)IN_F;  // zero-row pad
    __syncthreads();

    // ---- r = 2 * x @ wT on own OUT-half (fp64; maintained incrementally) ----
    double r[8];
#pragma unroll
    for (int s = 0; s < 8; ++s) r[s] = 0.0;
    if constexpr (MODE == 1) {
#pragma unroll 1
        for (int k = 0; k < cnt; k += 2) half_add2(r, wT, act[k], act[k + 1], lane, wv);
    } else {
#pragma unroll 1
        for (int k = 0; k < cnt; ++k) half_add0(r, w, act[k], lane, wv);
    }
#pragma unroll
    for (int s = 0; s < 8; ++s) r[s] *= 2.0;

    double vd[8];  // FULL v = encoded @ W, duplicated on both waves
#pragma unroll
    for (int p = 0; p < 8; ++p) vd[p] = 0.0;

    unsigned enc = 0;      // per-lane 8-bit slot mask over own OUT slots
    unsigned selmask = 0;  // final-step xr slots (identical on both waves)
    int O0 = -1, O1 = -1, O2 = -1, O3 = -1, O4 = -1, O5 = -1;  // uniform

#pragma unroll 1
    for (int t = 0; t < K_ACTIVE; ++t) {
        // ---- argmax of residual over non-encoded j, local on own half ----
        unsigned k8[8];  // transient u32 keys, alive through the cross merge
#pragma unroll
        for (int s = 0; s < 8; ++s) {
            const unsigned key = hi_key(r[s]);
            k8[s] = (enc & (1u << s)) ? 0u : key;
        }
        {
            unsigned lm = k8[0];
#pragma unroll
            for (int s = 1; s < 8; ++s) lm = k8[s] > lm ? k8[s] : lm;
            const unsigned g = wave_umax(lm);
            const unsigned long long tied = __ballot(lm == g);
            unsigned mm = 0;
#pragma unroll
            for (int s = 0; s < 8; ++s) mm |= (k8[s] == g) ? (1u << s) : 0u;
            const int L = (int)__ffsll((long long)tied) - 1;
            const unsigned mmL = (unsigned)__builtin_amdgcn_readlane((int)mm, L);
            int jw;
            if (__builtin_expect((__popcll(tied) == 1) && !(mmL & (mmL - 1)), 1)) {
                const int bi = __ffs(mmL) - 1;  // slot asc == j asc within lane
                jw = (wv << 9) | ((bi >> 2) << 8) | (L << 2) | (bi & 3);
            } else {  // exact intra-wave resolve among u32-tied candidates
                unsigned long long kb = 0;
#pragma unroll
                for (int s = 0; s < 8; ++s) {
                    const int j = (wv << 9) | ((s >> 2) << 8) | (lane << 2) | (s & 3);
                    const unsigned long long fk =
                        pack_key(r[s], 1023u ^ (unsigned)j, 1023ull);
                    kb = (k8[s] == g && fk > kb) ? fk : kb;
                }
                const unsigned long long gk = wave_max_key(kb);
                jw = 1023 ^ (int)(gk & 1023ull);
            }
            if (lane == 0) {
                gu32[t & 1][wv] = g;
                gjw[t & 1][wv] = jw;
            }
        }
        __syncthreads();  // B1: the ONLY barrier per step
        const unsigned ga = gu32[t & 1][0], gb = gu32[t & 1][1];
        int bestj;
        if (__builtin_expect(ga != gb, 1)) {  // u32 strict order is f64-faithful
            bestj = (gb > ga) ? gjw[t & 1][1] : gjw[t & 1][0];
        } else {  // rare: exact cross-wave u64 merge (uniform branch, own barrier)
            unsigned long long kb = 0;
#pragma unroll
            for (int s = 0; s < 8; ++s) {
                const int j = (wv << 9) | ((s >> 2) << 8) | (lane << 2) | (s & 3);
                const unsigned long long fk =
                    pack_key(r[s], 1023u ^ (unsigned)j, 1023ull);
                kb = (k8[s] == ga && fk > kb) ? fk : kb;
            }
            const unsigned long long wm = wave_max_key(kb);
            if (lane == 0) kx[wv] = wm;
            __syncthreads();
            const unsigned long long A = kx[0], B = kx[1];
            bestj = 1023 ^ (int)((A > B ? A : B) & 1023ull);
        }
        bestj = __builtin_amdgcn_readfirstlane(bestj);
        if ((bestj >> 9) == wv && ((bestj >> 2) & 63) == lane)
            enc |= 1u << ((((bestj >> 8) & 1) << 2) | (bestj & 3));

        // ---- v += W[bestj][:] — BOTH waves (duplicated, L2-hit loads) ----
        {
            const float* wr = w + ((size_t)bestj << 9) + (lane << 2);
            const float4 f0 = *(const float4*)wr;
            const float4 f1 = *(const float4*)(wr + 256);
            vd[0] += (double)f0.x;  vd[1] += (double)f0.y;
            vd[2] += (double)f0.z;  vd[3] += (double)f0.w;
            vd[4] += (double)f1.x;  vd[5] += (double)f1.y;
            vd[6] += (double)f1.z;  vd[7] += (double)f1.w;
        }

        // ---- kwta: top-6 of v — BOTH waves, identical, wave-local, no barrier ----
        int N0, N1, N2, N3, N4, N5;
        {
            unsigned kk[8];  // transient u32
#pragma unroll
            for (int p = 0; p < 8; ++p) kk[p] = hi_key(vd[p]);
            int N[6];
#pragma unroll
            for (int s2 = 0; s2 < K_IN; ++s2) {
                unsigned lm = kk[0];
#pragma unroll
                for (int p = 1; p < 8; ++p) lm = kk[p] > lm ? kk[p] : lm;
                const unsigned g2 = wave_umax(lm);
                const unsigned long long tied2 = __ballot(lm == g2);
                unsigned mm2 = 0;
#pragma unroll
                for (int p = 0; p < 8; ++p) mm2 |= (kk[p] == g2) ? (1u << p) : 0u;
                const int L2 = (int)__ffsll((long long)tied2) - 1;
                const unsigned mmL2 =
                    (unsigned)__builtin_amdgcn_readlane((int)mm2, L2);
                int n;
                if (__builtin_expect((__popcll(tied2) == 1) && !(mmL2 & (mmL2 - 1)),
                                     1)) {
                    const int bp = __ffs(mmL2) - 1;
                    n = ((bp >> 2) << 8) | (L2 << 2) | (bp & 3);
                    // unique candidate: clear by value (exactly one slot matches)
#pragma unroll
                    for (int p = 0; p < 8; ++p) kk[p] = (kk[p] == g2) ? 0u : kk[p];
                } else {  // exact resolve among u32-tied candidates
                    unsigned long long kb = 0;
#pragma unroll
                    for (int p = 0; p < 8; ++p) {
                        const int i = ((p >> 2) << 8) | (lane << 2) | (p & 3);
                        const unsigned long long fk =
                            pack_key(vd[p], 511u ^ (unsigned)i, 511ull);
                        kb = (kk[p] == g2 && fk > kb) ? fk : kb;
                    }
                    const unsigned long long gk = wave_max_key(kb);
                    n = 511 ^ (int)(gk & 511ull);
                    const int ln = (n >> 2) & 63;
                    const int bp = (((n >> 8) & 1) << 2) | (n & 3);
#pragma unroll
                    for (int p = 0; p < 8; ++p)
                        kk[p] = (lane == ln && p == bp) ? 0u : kk[p];
                }
                N[s2] = __builtin_amdgcn_readfirstlane(n);
            }
            if (t == K_ACTIVE - 1) {
                selmask = 0;  // cleared keys are 0 (0 unreachable for real values)
#pragma unroll
                for (int p = 0; p < 8; ++p) selmask |= (kk[p] == 0u) ? (1u << p) : 0u;
            }
            N0 = N[0]; N1 = N[1]; N2 = N[2]; N3 = N[3]; N4 = N[4]; N5 = N[5];
        }

        // ---- incremental residual update on own half: set-diff of xr ----
        if (t == 0) {
            if constexpr (MODE == 1) {
                half_axpy(r, wT, N0, -1.0, lane, wv);
                half_axpy(r, wT, N1, -1.0, lane, wv);
                half_axpy(r, wT, N2, -1.0, lane, wv);
                half_axpy(r, wT, N3, -1.0, lane, wv);
                half_axpy(r, wT, N4, -1.0, lane, wv);
                half_axpy(r, wT, N5, -1.0, lane, wv);
            } else {
                half_axpy0(r, w, N0, -1.0, lane, wv);
                half_axpy0(r, w, N1, -1.0, lane, wv);
                half_axpy0(r, w, N2, -1.0, lane, wv);
                half_axpy0(r, w, N3, -1.0, lane, wv);
                half_axpy0(r, w, N4, -1.0, lane, wv);
                half_axpy0(r, w, N5, -1.0, lane, wv);
            }
        } else if (t < K_ACTIVE - 1) {
#pragma unroll
            for (int a2 = 0; a2 < 6; ++a2) {
                const int o = (a2 == 0) ? O0 : (a2 == 1) ? O1 : (a2 == 2) ? O2
                              : (a2 == 3) ? O3 : (a2 == 4) ? O4 : O5;
                const bool stay = (o == N0) | (o == N1) | (o == N2) |
                                  (o == N3) | (o == N4) | (o == N5);
                if (!stay) {
                    if constexpr (MODE == 1) half_axpy(r, wT, o, 1.0, lane, wv);
                    else half_axpy0(r, w, o, 1.0, lane, wv);
                }
            }
#pragma unroll
            for (int b2 = 0; b2 < 6; ++b2) {
                const int n = (b2 == 0) ? N0 : (b2 == 1) ? N1 : (b2 == 2) ? N2
                              : (b2 == 3) ? N3 : (b2 == 4) ? N4 : N5;
                const bool was = (n == O0) | (n == O1) | (n == O2) |
                                 (n == O3) | (n == O4) | (n == O5);
                if (!was) {
                    if constexpr (MODE == 1) half_axpy(r, wT, n, -1.0, lane, wv);
                    else half_axpy0(r, w, n, -1.0, lane, wv);
                }
            }
        }
        O0 = N0; O1 = N1; O2 = N2; O3 = N3; O4 = N4; O5 = N5;
    }

    // ---- outputs: encoded halves (each wave), xr (wave0), coalesced float4 ----
    float* oe = out + (size_t)row * OUT_F + (wv << 9) + (lane << 2);
#pragma unroll
    for (int c = 0; c < 2; ++c) {
        float4 v;
        v.x = (enc & (1u << (4 * c + 0))) ? 1.0f : 0.0f;
        v.y = (enc & (1u << (4 * c + 1))) ? 1.0f : 0.0f;
        v.z = (enc & (1u << (4 * c + 2))) ? 1.0f : 0.0f;
        v.w = (enc & (1u << (4 * c + 3))) ? 1.0f : 0.0f;
        *(float4*)(oe + (c << 8)) = v;
    }
    if (wv == 0) {
        float* ox = out + (size_t)rows * OUT_F + (size_t)row * IN_F + (lane << 2);
#pragma unroll
        for (int c = 0; c < 2; ++c) {
            float4 v;
            v.x = (selmask & (1u << (4 * c + 0))) ? 1.0f : 0.0f;
            v.y = (selmask & (1u << (4 * c + 1))) ? 1.0f : 0.0f;
            v.z = (selmask & (1u << (4 * c + 2))) ? 1.0f : 0.0f;
            v.w = (selmask & (1u << (4 * c + 3))) ? 1.0f : 0.0f;
            *(float4*)(ox + (c << 8)) = v;
        }
    }
}

extern "C" void kernel_launch(void* const* d_in, const int* in_sizes, int n_in,
                              void* d_out, int out_size, void* d_ws, size_t ws_size,
                              hipStream_t stream) {
    const float* x = (const float*)d_in[0];
    const float* w = (const float*)d_in[1];
    float* out = (float*)d_out;
    const int rows = in_sizes[0] / IN_F;  // 4096

    const size_t need_f = (size_t)(IN_F + 1) * OUT_F * sizeof(float);  // 2.1 MB

    if (d_ws != nullptr && ws_size >= need_f) {
        float* wT = (float*)d_ws;
        transpose_w_kernel<<<dim3(IN_F / 32, OUT_F / 32), 256, 0, stream>>>(w, wT);
        zero_row_f_kernel<<<OUT_F / 256, 256, 0, stream>>>(wT);
        bmp_kernel<1><<<rows, 128, 0, stream>>>(x, w, wT, out, rows);
    } else {
        bmp_kernel<0><<<rows, 128, 0, stream>>>(x, w, nullptr, out, rows);
    }
}